// Round 21
// baseline (306.788 us; speedup 1.0000x reference)
//
#include <hip/hip_runtime.h>
#include <hip/hip_bf16.h>

typedef unsigned short u16;
typedef __attribute__((ext_vector_type(8))) short short8;   // 8 x bf16 (4 VGPR)
typedef __attribute__((ext_vector_type(4))) short s16x4;
typedef __attribute__((ext_vector_type(4))) float f32x4;

#define T_SEQ  4096
#define HEADS  16
#define HDIM   64
#define CDIM   1024
#define MDIM   8192              // B*T
#define HSZ    (T_SEQ * HDIM)    // elems per (b,h) head-plane
#define SEC    8388608           // elems per qkv section = B*T*C
// q pre-scale: (1/sqrt(64)) * log2(e) -> softmax in exp2 domain, no max-sub
#define QSCALE 0.1803368801111244f

__device__ __forceinline__ u16 f2bf(float f) {
    __hip_bfloat16 h = __float2bfloat16(f);
    u16 u; __builtin_memcpy(&u, &h, 2);
    return u;
}

// ---------------------------------------------------------------------------
// fp32 -> bf16 cast, 4 elems/thread.
// ---------------------------------------------------------------------------
__global__ __launch_bounds__(256) void cast_k(const float* __restrict__ in,
                                              u16* __restrict__ out, int n4) {
    const int i = blockIdx.x * 256 + threadIdx.x;
    if (i < n4) {
        f32x4 v = ((const f32x4*)in)[i];
        s16x4 o;
        #pragma unroll
        for (int j = 0; j < 4; ++j) o[j] = (short)f2bf(v[j]);
        ((s16x4*)out)[i] = o;
    }
}

// ---------------------------------------------------------------------------
// Batched transpose: out[z][c][r'] = (bf16)in[z][r][c].  R,C multiples of 32.
// PERM5: permute low-5 bits of the output inner index (key order for vT):
//   pos(k) = 8*((k&15)>>2) + (k&3) + 4*((k>>4)&1)  -- matches attn's in-reg
//   P fragment order so PV sums over identically-permuted key positions.
// grid (C/32, R/32, Z), block (32,8)
// ---------------------------------------------------------------------------
template <int IN_F32, int PERM5>
__global__ __launch_bounds__(256) void transpose_k(const void* __restrict__ in_,
                                                   u16* __restrict__ out,
                                                   int R, int C) {
    __shared__ u16 tile[32][33];
    const size_t zoff = (size_t)blockIdx.z * R * C;
    const int c0 = blockIdx.x * 32, r0 = blockIdx.y * 32;
    const int tx = threadIdx.x, ty = threadIdx.y;
    #pragma unroll
    for (int i = ty; i < 32; i += 8) {
        const size_t idx = zoff + (size_t)(r0 + i) * C + c0 + tx;
        tile[i][tx] = IN_F32 ? f2bf(((const float*)in_)[idx])
                             : ((const u16*)in_)[idx];
    }
    __syncthreads();
    const int txo = PERM5 ? (((tx & 12) << 1) + (tx & 3) + ((tx & 16) >> 2)) : tx;
    #pragma unroll
    for (int i = ty; i < 32; i += 8)
        out[zoff + (size_t)(c0 + i) * R + r0 + txo] = tile[tx][i];
}

// ---------------------------------------------------------------------------
// bf16 GEMM: C[m][n] = sum_k A[m][k] * Bt[n][k] + bias[n]   (bias fp32)
//   128x128 tile, BK=64, 4 waves (2x2), 16x16x32 MFMA, XOR-swizzled LDS.
// Staging via global_load_lds width=16 (r17): LINEAR LDS dest + pre-inverse-
// swizzled global source; read path unchanged.
// MODE 0: qkv epilogue -> q->qws (bf16, scaled by QSCALE); k/v -> outp
//         fp32 head layout; k additionally -> kbf (bf16) when non-null.
// MODE 1: proj epilogue -> y row-major fp32
// grid (N/128, MDIM/128), block 256
// ---------------------------------------------------------------------------
template <int MODE>
__global__ __launch_bounds__(256) void gemm_k(const u16* __restrict__ A,
                                              const u16* __restrict__ Bt,
                                              const float* __restrict__ bias,
                                              float* __restrict__ outp,
                                              u16* __restrict__ qws,
                                              u16* __restrict__ kbf, int K) {
    __shared__ unsigned char sA[16384];   // [128 rows][64 k] bf16, 128B rows
    __shared__ unsigned char sB[16384];
    const int tid  = threadIdx.x;
    const int lane = tid & 63;
    const int w = tid >> 6, wr = w >> 1, wc = w & 1;
    const int m0 = blockIdx.y * 128, n0 = blockIdx.x * 128;
    const int fr = lane & 15, fg = lane >> 4;

    f32x4 acc[4][4] = {};

    // global_load_lds staging geometry (per wave: 4 chunks x 8 rows each)
    const int lrow  = lane >> 3;                    // row within 8-row chunk
    const int gcole = ((lane & 7) ^ lrow) << 3;     // inverse-swizzled src col
    const u16* gaw = A  + (size_t)(m0 + w * 32 + lrow) * K + gcole;
    const u16* gbw = Bt + (size_t)(n0 + w * 32 + lrow) * K + gcole;
    const int rswz = (fr & 7) << 4;                 // read swizzle (unchanged)

    const int nk = K >> 6;
    for (int kt = 0; kt < nk; ++kt) {
        __syncthreads();   // prior tile's LDS reads complete before DMA lands
        #pragma unroll
        for (int i = 0; i < 4; ++i) {
            __builtin_amdgcn_global_load_lds(
                (const __attribute__((address_space(1))) void*)(gaw + (size_t)i * 8 * K),
                (__attribute__((address_space(3))) void*)(sA + w * 4096 + i * 1024),
                16, 0, 0);
            __builtin_amdgcn_global_load_lds(
                (const __attribute__((address_space(1))) void*)(gbw + (size_t)i * 8 * K),
                (__attribute__((address_space(3))) void*)(sB + w * 4096 + i * 1024),
                16, 0, 0);
        }
        gaw += 64; gbw += 64;
        __syncthreads();   // vmcnt(0) drain: tile visible

        #pragma unroll
        for (int kk = 0; kk < 2; ++kk) {
            short8 af[4], bf[4];
            #pragma unroll
            for (int m = 0; m < 4; ++m)
                af[m] = *(const short8*)(sA + (wr*64 + m*16 + fr) * 128 +
                                         ((kk*64 + fg*16) ^ rswz));
            #pragma unroll
            for (int n = 0; n < 4; ++n)
                bf[n] = *(const short8*)(sB + (wc*64 + n*16 + fr) * 128 +
                                         ((kk*64 + fg*16) ^ rswz));
            #pragma unroll
            for (int m = 0; m < 4; ++m)
                #pragma unroll
                for (int n = 0; n < 4; ++n)
                    acc[m][n] = __builtin_amdgcn_mfma_f32_16x16x32_bf16(
                        af[m], bf[n], acc[m][n], 0, 0, 0);
        }
    }

    // epilogue: C/D layout col = lane&15, row = (lane>>4)*4 + reg  [m89]
    #pragma unroll
    for (int n = 0; n < 4; ++n) {
        const int gn = n0 + wc*64 + n*16 + fr;
        const float bn = bias[gn];
        if (MODE == 0) {
            const int s = gn >> 10;               // 0=q 1=k 2=v
            const int c = gn & 1023;
            const int h = c >> 6, d = c & 63;
            if (s == 0) {
                #pragma unroll
                for (int m = 0; m < 4; ++m)
                    #pragma unroll
                    for (int r = 0; r < 4; ++r) {
                        const int gm = m0 + wr*64 + m*16 + fg*4 + r;
                        const int b = gm >> 12, t = gm & 4095;
                        qws[(size_t)((b << 4) + h) * HSZ + (size_t)t * HDIM + d] =
                            f2bf((acc[m][n][r] + bn) * QSCALE);
                    }
            } else {
                float* fdst = outp + (size_t)s * SEC;
                #pragma unroll
                for (int m = 0; m < 4; ++m)
                    #pragma unroll
                    for (int r = 0; r < 4; ++r) {
                        const int gm = m0 + wr*64 + m*16 + fg*4 + r;
                        const int b = gm >> 12, t = gm & 4095;
                        const size_t hidx =
                            (size_t)((b << 4) + h) * HSZ + (size_t)t * HDIM + d;
                        const float v = acc[m][n][r] + bn;
                        fdst[hidx] = v;
                        if (s == 1 && kbf) kbf[hidx] = f2bf(v);  // bf16 K copy
                    }
            }
        } else {
            #pragma unroll
            for (int m = 0; m < 4; ++m)
                #pragma unroll
                for (int r = 0; r < 4; ++r) {
                    const int gm = m0 + wr*64 + m*16 + fg*4 + r;
                    outp[(size_t)gm * CDIM + gn] = acc[m][n][r] + bn;
                }
        }
    }
}

// ---------------------------------------------------------------------------
// Flash attention fwd (causal) -- r20 body, single delta: UNPAIRED grid.
// Grid 2048, ONE qblk per block; complementary qblk mapping keeps per-CU
// work constant under round-robin dispatch: blocks {wg, wg+256, ...} on one
// CU carry qblks {idx, 63-idx} x 4 bh -> 4*[(idx+1)+(64-idx)] = 260 rounds,
// idx-independent. 8 blocks/CU x 16KB LDS = 128KB; 32 waves/CU (2x r20).
// Body byte-identical to r20 (KVBLK=64 rounds, swapped QK^T, in-reg P,
// exp2 no-max softmax).
//   q: (BH,T,64) bf16 (QSCALE-scaled)   vt: (BH,64,T) bf16 key-permuted
//   att out: (B, T, H*64) bf16
// ---------------------------------------------------------------------------
template <int KBF>
__global__ __launch_bounds__(256) void attn_k(const u16* __restrict__ q,
                                              const float* __restrict__ kf32,
                                              const u16* __restrict__ kb16,
                                              const u16* __restrict__ vt,
                                              u16* __restrict__ att) {
    __shared__ unsigned char sK[8192];   // [64 key][64 d]  128B rows
    __shared__ unsigned char sV[8192];   // [64 d][64 pos]  128B rows (permuted)
    const int wg   = blockIdx.x;           // 0..2047
    const int xcd  = wg & 7;
    const int j    = wg >> 3;              // 0..255
    const int half = j >> 7;               // 0 or 1
    const int jj   = j & 127;              // 0..127
    const int bh   = xcd * 4 + (jj >> 5);
    const int idx  = jj & 31;
    const int qblk = half ? (63 - idx) : idx;
    const int tid = threadIdx.x, lane = tid & 63, w = tid >> 6;
    const int fr = lane & 15, fg = lane >> 4;
    const size_t hbase = (size_t)bh * HSZ;

    // staging: thread covers 32B (2x16B) of one 128B row, for K and V
    const int srow  = tid >> 2;            // 0..63: key row (K) / d row (V)
    const int scolb = (tid & 3) * 32;      // byte offset in row
    const int swz   = (srow & 7) << 4;
    const int rswz  = (fr & 7) << 4;       // read swizzle (rows = ...+fr)

    const float* gkf = kf32 ? kf32 + hbase + (size_t)srow * 64 + (tid & 3) * 16 : nullptr;
    const u16*   gkb = kb16 ? kb16 + hbase + (size_t)srow * 64 + (tid & 3) * 16 : nullptr;
    const u16*   gv  = vt + hbase + (size_t)srow * T_SEQ + (tid & 3) * 16;
    unsigned char* sKw = sK + srow * 128;
    unsigned char* sVw = sV + srow * 128;
    const int b = bh >> 4, h = bh & 15;

    const int q0 = qblk * 64 + w * 16;

    const short8 qf0 = *(const short8*)(q + hbase + (size_t)(q0 + fr) * 64 + fg * 8);
    const short8 qf1 = *(const short8*)(q + hbase + (size_t)(q0 + fr) * 64 + 32 + fg * 8);

    f32x4 o[4] = {};
    float ssum = 0.f;                 // per-lane: partial sum for q=fr

    const int n64 = qblk + 1;         // 64-key staging rounds
    for (int k64 = 0; k64 < n64; ++k64) {
        short8 kv0, kv1;
        if (KBF) {
            kv0 = *(const short8*)(gkb + (size_t)k64 * 4096);
            kv1 = *(const short8*)(gkb + (size_t)k64 * 4096 + 8);
        } else {
            f32x4 a0 = *(const f32x4*)(gkf + (size_t)k64 * 4096);
            f32x4 a1 = *(const f32x4*)(gkf + (size_t)k64 * 4096 + 4);
            f32x4 a2 = *(const f32x4*)(gkf + (size_t)k64 * 4096 + 8);
            f32x4 a3 = *(const f32x4*)(gkf + (size_t)k64 * 4096 + 12);
            #pragma unroll
            for (int jx = 0; jx < 4; ++jx) {
                kv0[jx]     = (short)f2bf(a0[jx]);
                kv0[4 + jx] = (short)f2bf(a1[jx]);
                kv1[jx]     = (short)f2bf(a2[jx]);
                kv1[4 + jx] = (short)f2bf(a3[jx]);
            }
        }
        short8 vv0 = *(const short8*)(gv + k64 * 64);
        short8 vv1 = *(const short8*)(gv + k64 * 64 + 8);
        __syncthreads();   // prior sub-tiles' LDS reads done before write
        *(short8*)(sKw + ((scolb)      ^ swz)) = kv0;
        *(short8*)(sKw + ((scolb + 16) ^ swz)) = kv1;
        *(short8*)(sVw + ((scolb)      ^ swz)) = vv0;
        *(short8*)(sVw + ((scolb + 16) ^ swz)) = vv1;
        __syncthreads();

        #pragma unroll
        for (int tt = 0; tt < 2; ++tt) {
            const int kb2 = k64 * 64 + tt * 32;

            // SWAPPED S = K Q^T: lane holds keys {kb2+4fg+r, kb2+16+4fg+r}
            // of q = q0+fr.  (tt*32+kh*16+fr)&7 == fr&7 -> rswz valid.
            f32x4 z[2];
            #pragma unroll
            for (int kh = 0; kh < 2; ++kh) {
                const unsigned char* Kr = sK + (tt*32 + kh*16 + fr) * 128;
                short8 kfa = *(const short8*)(Kr + ((fg*16) ^ rswz));
                short8 kfb = *(const short8*)(Kr + ((64 + fg*16) ^ rswz));
                f32x4 zz = {0.f, 0.f, 0.f, 0.f};
                zz = __builtin_amdgcn_mfma_f32_16x16x32_bf16(kfa, qf0, zz, 0, 0, 0);
                zz = __builtin_amdgcn_mfma_f32_16x16x32_bf16(kfb, qf1, zz, 0, 0, 0);
                z[kh] = zz;
            }

            const bool full = (kb2 + 31 <= q0);   // wave-uniform
            const int kq = kb2 + fg * 4;          // z0 key base, this lane
            const int qg = q0 + fr;
            float p[8];
            #pragma unroll
            for (int r = 0; r < 4; ++r) {
                float s0 = z[0][r], s1 = z[1][r];
                if (!full) {
                    s0 = (kq + r      <= qg) ? s0 : -1e30f;
                    s1 = (kq + 16 + r <= qg) ? s1 : -1e30f;
                }
                p[r]     = exp2f(s0);             // native v_exp_f32
                p[4 + r] = exp2f(s1);
            }
            ssum += p[0] + p[1] + p[2] + p[3] + p[4] + p[5] + p[6] + p[7];

            // pack P A-frag in-register (pos-order matches PERM5)
            unsigned int pw0, pw1, pw2, pw3;
            asm("v_cvt_pk_bf16_f32 %0, %1, %2" : "=v"(pw0) : "v"(p[0]), "v"(p[1]));
            asm("v_cvt_pk_bf16_f32 %0, %1, %2" : "=v"(pw1) : "v"(p[2]), "v"(p[3]));
            asm("v_cvt_pk_bf16_f32 %0, %1, %2" : "=v"(pw2) : "v"(p[4]), "v"(p[5]));
            asm("v_cvt_pk_bf16_f32 %0, %1, %2" : "=v"(pw3) : "v"(p[6]), "v"(p[7]));
            short8 pf;
            {
                unsigned int tmp[4] = {pw0, pw1, pw2, pw3};
                __builtin_memcpy(&pf, tmp, 16);
            }

            #pragma unroll
            for (int db = 0; db < 4; ++db) {
                const unsigned char* Vr = sV + (db*16 + fr) * 128;
                short8 vf = *(const short8*)(Vr + ((tt*64 + fg*16) ^ rswz));
                o[db] = __builtin_amdgcn_mfma_f32_16x16x32_bf16(pf, vf, o[db], 0, 0, 0);
            }
        }
    }

    // denominator: reduce ssum across fg groups (q=fr is lane-local)
    float rs = ssum;
    rs += __shfl_xor(rs, 16, 64);
    rs += __shfl_xor(rs, 32, 64);
    const float inv = 1.f / rs;       // inv for q = fr (uniform over fg)
    // output: o[db][r] = O[q=q0+fg*4+r][d=db*16+fr] -> fetch inv for that q
    #pragma unroll
    for (int r = 0; r < 4; ++r) {
        const float invq = __shfl(inv, (fg << 4) + (fg << 2) + r, 64);
        const int t = q0 + fg * 4 + r;
        #pragma unroll
        for (int db = 0; db < 4; ++db) {
            att[(size_t)(b * T_SEQ + t) * CDIM + h * 64 + db * 16 + fr] =
                f2bf(o[db][r] * invq);
        }
    }
}

// ---------------------------------------------------------------------------
// Orchestration. Inputs fp32 (by size), outputs fp32 (y,k,v).
// Workspace:
//   [ 0,16M)  q_ws bf16 (QSCALE-scaled);  wTp overlays after attn
//   [16,32M)  x_bf -> vT bf16 (key-permuted) after gemm0
//   [32,48M)  wTa -> attb bf16 after gemm0
//   [48,64M)  k_bf bf16 (ws_size >= 64 MiB confirmed in r12; fallback kept)
// ---------------------------------------------------------------------------
extern "C" void kernel_launch(void* const* d_in, const int* in_sizes, int n_in,
                              void* d_out, int out_size, void* d_ws, size_t ws_size,
                              hipStream_t stream) {
    (void)out_size;
    const float *x = nullptr, *w_attn = nullptr, *b_attn = nullptr,
                *w_proj = nullptr, *b_proj = nullptr;
    for (int i = 0; i < n_in; ++i) {
        switch (in_sizes[i]) {
            case 8388608: x      = (const float*)d_in[i]; break;
            case 3145728: w_attn = (const float*)d_in[i]; break;
            case 3072:    b_attn = (const float*)d_in[i]; break;
            case 1048576: w_proj = (const float*)d_in[i]; break;
            case 1024:    b_proj = (const float*)d_in[i]; break;
        }
    }
    if (!x || !w_attn || !b_attn || !w_proj || !b_proj) return;

    float* out = (float*)d_out;
    unsigned char* ws = (unsigned char*)d_ws;
    const bool big = ws_size >= (64ull << 20);

    u16* q_ws = (u16*)(ws);
    u16* wTp  = (u16*)(ws);
    u16* x_bf = (u16*)(ws + 16777216);
    u16* vT   = (u16*)(ws + 16777216);
    u16* wTa  = (u16*)(ws + 33554432);
    u16* attb = (u16*)(ws + 33554432);
    u16* k_bf = big ? (u16*)(ws + 50331648) : nullptr;

    cast_k<<<8192, 256, 0, stream>>>(x, x_bf, 2097152);
    transpose_k<1, 0><<<dim3(96, 32, 1), dim3(32, 8), 0, stream>>>(w_attn, wTa, 1024, 3072);
    gemm_k<0><<<dim3(24, 64), 256, 0, stream>>>(x_bf, wTa, b_attn, out, q_ws, k_bf, 1024);
    // v -> vT with PERM5 key permutation (matches attn's in-register P order)
    transpose_k<1, 1><<<dim3(2, 128, 32), dim3(32, 8), 0, stream>>>(out + 2 * (size_t)SEC, vT, 4096, 64);
    if (big)
        attn_k<1><<<2048, 256, 0, stream>>>(q_ws, nullptr, k_bf, vT, attb);
    else
        attn_k<0><<<2048, 256, 0, stream>>>(q_ws, out + SEC, nullptr, vT, attb);
    transpose_k<1, 0><<<dim3(32, 32, 1), dim3(32, 8), 0, stream>>>(w_proj, wTp, 1024, 1024);
    gemm_k<1><<<dim3(8, 64), 256, 0, stream>>>(attb, wTp, b_proj, out, nullptr, nullptr, 1024);
}

// Round 22
// 261.784 us; speedup vs baseline: 1.1719x; 1.1719x over previous
//
#include <hip/hip_runtime.h>
#include <hip/hip_bf16.h>

typedef unsigned short u16;
typedef __attribute__((ext_vector_type(8))) short short8;   // 8 x bf16 (4 VGPR)
typedef __attribute__((ext_vector_type(4))) short s16x4;
typedef __attribute__((ext_vector_type(4))) float f32x4;

#define T_SEQ  4096
#define HEADS  16
#define HDIM   64
#define CDIM   1024
#define MDIM   8192              // B*T
#define HSZ    (T_SEQ * HDIM)    // elems per (b,h) head-plane
#define SEC    8388608           // elems per qkv section = B*T*C
// q pre-scale: (1/sqrt(64)) * log2(e) -> softmax in exp2 domain, no max-sub
#define QSCALE 0.1803368801111244f

__device__ __forceinline__ u16 f2bf(float f) {
    __hip_bfloat16 h = __float2bfloat16(f);
    u16 u; __builtin_memcpy(&u, &h, 2);
    return u;
}

// ---------------------------------------------------------------------------
// fp32 -> bf16 cast, 4 elems/thread.
// ---------------------------------------------------------------------------
__global__ __launch_bounds__(256) void cast_k(const float* __restrict__ in,
                                              u16* __restrict__ out, int n4) {
    const int i = blockIdx.x * 256 + threadIdx.x;
    if (i < n4) {
        f32x4 v = ((const f32x4*)in)[i];
        s16x4 o;
        #pragma unroll
        for (int j = 0; j < 4; ++j) o[j] = (short)f2bf(v[j]);
        ((s16x4*)out)[i] = o;
    }
}

// ---------------------------------------------------------------------------
// Batched transpose: out[z][c][r'] = (bf16)in[z][r][c].  R,C multiples of 32.
// PERM5: permute low-5 bits of the output inner index (key order for vT):
//   pos(k) = 8*((k&15)>>2) + (k&3) + 4*((k>>4)&1)  -- matches attn's in-reg
//   P fragment order so PV sums over identically-permuted key positions.
// grid (C/32, R/32, Z), block (32,8)
// ---------------------------------------------------------------------------
template <int IN_F32, int PERM5>
__global__ __launch_bounds__(256) void transpose_k(const void* __restrict__ in_,
                                                   u16* __restrict__ out,
                                                   int R, int C) {
    __shared__ u16 tile[32][33];
    const size_t zoff = (size_t)blockIdx.z * R * C;
    const int c0 = blockIdx.x * 32, r0 = blockIdx.y * 32;
    const int tx = threadIdx.x, ty = threadIdx.y;
    #pragma unroll
    for (int i = ty; i < 32; i += 8) {
        const size_t idx = zoff + (size_t)(r0 + i) * C + c0 + tx;
        tile[i][tx] = IN_F32 ? f2bf(((const float*)in_)[idx])
                             : ((const u16*)in_)[idx];
    }
    __syncthreads();
    const int txo = PERM5 ? (((tx & 12) << 1) + (tx & 3) + ((tx & 16) >> 2)) : tx;
    #pragma unroll
    for (int i = ty; i < 32; i += 8)
        out[zoff + (size_t)(c0 + i) * R + r0 + txo] = tile[tx][i];
}

// ---------------------------------------------------------------------------
// bf16 GEMM: C[m][n] = sum_k A[m][k] * Bt[n][k] + bias[n]   (bias fp32)
//   128x128 tile, BK=64, 4 waves (2x2), 16x16x32 MFMA, XOR-swizzled LDS.
// Staging via global_load_lds width=16 (r17): LINEAR LDS dest + pre-inverse-
// swizzled global source; read path unchanged.
// MODE 0: qkv epilogue -> q->qws (bf16, scaled by QSCALE); k/v -> outp
//         fp32 head layout; k additionally -> kbf (bf16) when non-null.
// MODE 1: proj epilogue -> y row-major fp32
// grid (N/128, MDIM/128), block 256
// ---------------------------------------------------------------------------
template <int MODE>
__global__ __launch_bounds__(256) void gemm_k(const u16* __restrict__ A,
                                              const u16* __restrict__ Bt,
                                              const float* __restrict__ bias,
                                              float* __restrict__ outp,
                                              u16* __restrict__ qws,
                                              u16* __restrict__ kbf, int K) {
    __shared__ unsigned char sA[16384];   // [128 rows][64 k] bf16, 128B rows
    __shared__ unsigned char sB[16384];
    const int tid  = threadIdx.x;
    const int lane = tid & 63;
    const int w = tid >> 6, wr = w >> 1, wc = w & 1;
    const int m0 = blockIdx.y * 128, n0 = blockIdx.x * 128;
    const int fr = lane & 15, fg = lane >> 4;

    f32x4 acc[4][4] = {};

    // global_load_lds staging geometry (per wave: 4 chunks x 8 rows each)
    const int lrow  = lane >> 3;                    // row within 8-row chunk
    const int gcole = ((lane & 7) ^ lrow) << 3;     // inverse-swizzled src col
    const u16* gaw = A  + (size_t)(m0 + w * 32 + lrow) * K + gcole;
    const u16* gbw = Bt + (size_t)(n0 + w * 32 + lrow) * K + gcole;
    const int rswz = (fr & 7) << 4;                 // read swizzle (unchanged)

    const int nk = K >> 6;
    for (int kt = 0; kt < nk; ++kt) {
        __syncthreads();   // prior tile's LDS reads complete before DMA lands
        #pragma unroll
        for (int i = 0; i < 4; ++i) {
            __builtin_amdgcn_global_load_lds(
                (const __attribute__((address_space(1))) void*)(gaw + (size_t)i * 8 * K),
                (__attribute__((address_space(3))) void*)(sA + w * 4096 + i * 1024),
                16, 0, 0);
            __builtin_amdgcn_global_load_lds(
                (const __attribute__((address_space(1))) void*)(gbw + (size_t)i * 8 * K),
                (__attribute__((address_space(3))) void*)(sB + w * 4096 + i * 1024),
                16, 0, 0);
        }
        gaw += 64; gbw += 64;
        __syncthreads();   // vmcnt(0) drain: tile visible

        #pragma unroll
        for (int kk = 0; kk < 2; ++kk) {
            short8 af[4], bf[4];
            #pragma unroll
            for (int m = 0; m < 4; ++m)
                af[m] = *(const short8*)(sA + (wr*64 + m*16 + fr) * 128 +
                                         ((kk*64 + fg*16) ^ rswz));
            #pragma unroll
            for (int n = 0; n < 4; ++n)
                bf[n] = *(const short8*)(sB + (wc*64 + n*16 + fr) * 128 +
                                         ((kk*64 + fg*16) ^ rswz));
            #pragma unroll
            for (int m = 0; m < 4; ++m)
                #pragma unroll
                for (int n = 0; n < 4; ++n)
                    acc[m][n] = __builtin_amdgcn_mfma_f32_16x16x32_bf16(
                        af[m], bf[n], acc[m][n], 0, 0, 0);
        }
    }

    // epilogue: C/D layout col = lane&15, row = (lane>>4)*4 + reg  [m89]
    #pragma unroll
    for (int n = 0; n < 4; ++n) {
        const int gn = n0 + wc*64 + n*16 + fr;
        const float bn = bias[gn];
        if (MODE == 0) {
            const int s = gn >> 10;               // 0=q 1=k 2=v
            const int c = gn & 1023;
            const int h = c >> 6, d = c & 63;
            if (s == 0) {
                #pragma unroll
                for (int m = 0; m < 4; ++m)
                    #pragma unroll
                    for (int r = 0; r < 4; ++r) {
                        const int gm = m0 + wr*64 + m*16 + fg*4 + r;
                        const int b = gm >> 12, t = gm & 4095;
                        qws[(size_t)((b << 4) + h) * HSZ + (size_t)t * HDIM + d] =
                            f2bf((acc[m][n][r] + bn) * QSCALE);
                    }
            } else {
                float* fdst = outp + (size_t)s * SEC;
                #pragma unroll
                for (int m = 0; m < 4; ++m)
                    #pragma unroll
                    for (int r = 0; r < 4; ++r) {
                        const int gm = m0 + wr*64 + m*16 + fg*4 + r;
                        const int b = gm >> 12, t = gm & 4095;
                        const size_t hidx =
                            (size_t)((b << 4) + h) * HSZ + (size_t)t * HDIM + d;
                        const float v = acc[m][n][r] + bn;
                        fdst[hidx] = v;
                        if (s == 1 && kbf) kbf[hidx] = f2bf(v);  // bf16 K copy
                    }
            }
        } else {
            #pragma unroll
            for (int m = 0; m < 4; ++m)
                #pragma unroll
                for (int r = 0; r < 4; ++r) {
                    const int gm = m0 + wr*64 + m*16 + fg*4 + r;
                    outp[(size_t)gm * CDIM + gn] = acc[m][n][r] + bn;
                }
        }
    }
}

// ---------------------------------------------------------------------------
// Flash attention fwd (causal) -- r20 structure (158 us baseline: grid 1024
// paired, KVBLK=64, swapped QK^T, in-reg P, exp2 no-max softmax).
// Single delta r22: DENOMINATOR VIA ONES-COLUMN MFMA. o4 = P @ ones
// accumulates the softmax row-sum on the (19%-utilized) MFMA pipe in the
// same C-layout as o[db] -> deletes 16 VALU adds/round (serial chain after
// exp2) AND the end-of-phase shfl reduces (invq = 1/o4[r] directly).
// Denominator sums bf16(P) = identical quantization to the PV numerator.
//   q: (BH,T,64) bf16 (QSCALE-scaled)   vt: (BH,64,T) bf16 key-permuted
//   att out: (B, T, H*64) bf16
// grid 1024 (=8 XCD x 4 bh x 32 pairs), block 256.
// ---------------------------------------------------------------------------
template <int KBF>
__global__ __launch_bounds__(256) void attn_k(const u16* __restrict__ q,
                                              const float* __restrict__ kf32,
                                              const u16* __restrict__ kb16,
                                              const u16* __restrict__ vt,
                                              u16* __restrict__ att) {
    __shared__ unsigned char sK[8192];   // [64 key][64 d]  128B rows
    __shared__ unsigned char sV[8192];   // [64 d][64 pos]  128B rows (permuted)
    const int wg  = blockIdx.x;            // 0..1023
    const int xcd = wg & 7;
    const int i   = wg >> 3;               // 0..127
    const int bh  = xcd * 4 + (i >> 5);
    const int pair = i & 31;
    const int tid = threadIdx.x, lane = tid & 63, w = tid >> 6;
    const int fr = lane & 15, fg = lane >> 4;
    const size_t hbase = (size_t)bh * HSZ;

    // staging: thread covers 32B (2x16B) of one 128B row, for K and V
    const int srow  = tid >> 2;            // 0..63: key row (K) / d row (V)
    const int scolb = (tid & 3) * 32;      // byte offset in row
    const int swz   = (srow & 7) << 4;
    const int rswz  = (fr & 7) << 4;       // read swizzle (rows = ...+fr)

    const float* gkf = kf32 ? kf32 + hbase + (size_t)srow * 64 + (tid & 3) * 16 : nullptr;
    const u16*   gkb = kb16 ? kb16 + hbase + (size_t)srow * 64 + (tid & 3) * 16 : nullptr;
    const u16*   gv  = vt + hbase + (size_t)srow * T_SEQ + (tid & 3) * 16;
    unsigned char* sKw = sK + srow * 128;
    unsigned char* sVw = sV + srow * 128;
    const int b = bh >> 4, h = bh & 15;

    // constant all-ones bf16 B-fragment (1.0 = 0x3F80)
    short8 ones;
    #pragma unroll
    for (int j = 0; j < 8; ++j) ones[j] = (short)0x3F80;

    #pragma unroll
    for (int ph = 0; ph < 2; ++ph) {
        const int qblk = ph ? 63 - pair : pair;
        const int q0 = qblk * 64 + w * 16;

        const short8 qf0 = *(const short8*)(q + hbase + (size_t)(q0 + fr) * 64 + fg * 8);
        const short8 qf1 = *(const short8*)(q + hbase + (size_t)(q0 + fr) * 64 + 32 + fg * 8);

        f32x4 o[4] = {};
        f32x4 o4 = {};                    // denominator accumulator (P @ ones)

        const int n64 = qblk + 1;         // 64-key staging rounds
        for (int k64 = 0; k64 < n64; ++k64) {
            short8 kv0, kv1;
            if (KBF) {
                kv0 = *(const short8*)(gkb + (size_t)k64 * 4096);
                kv1 = *(const short8*)(gkb + (size_t)k64 * 4096 + 8);
            } else {
                f32x4 a0 = *(const f32x4*)(gkf + (size_t)k64 * 4096);
                f32x4 a1 = *(const f32x4*)(gkf + (size_t)k64 * 4096 + 4);
                f32x4 a2 = *(const f32x4*)(gkf + (size_t)k64 * 4096 + 8);
                f32x4 a3 = *(const f32x4*)(gkf + (size_t)k64 * 4096 + 12);
                #pragma unroll
                for (int j = 0; j < 4; ++j) {
                    kv0[j]     = (short)f2bf(a0[j]);
                    kv0[4 + j] = (short)f2bf(a1[j]);
                    kv1[j]     = (short)f2bf(a2[j]);
                    kv1[4 + j] = (short)f2bf(a3[j]);
                }
            }
            short8 vv0 = *(const short8*)(gv + k64 * 64);
            short8 vv1 = *(const short8*)(gv + k64 * 64 + 8);
            __syncthreads();   // prior sub-tiles' LDS reads done before write
            *(short8*)(sKw + ((scolb)      ^ swz)) = kv0;
            *(short8*)(sKw + ((scolb + 16) ^ swz)) = kv1;
            *(short8*)(sVw + ((scolb)      ^ swz)) = vv0;
            *(short8*)(sVw + ((scolb + 16) ^ swz)) = vv1;
            __syncthreads();

            #pragma unroll
            for (int tt = 0; tt < 2; ++tt) {
                const int kb2 = k64 * 64 + tt * 32;

                // SWAPPED S = K Q^T: lane holds keys {kb2+4fg+r, kb2+16+4fg+r}
                // of q = q0+fr.  (tt*32+kh*16+fr)&7 == fr&7 -> rswz valid.
                f32x4 z[2];
                #pragma unroll
                for (int kh = 0; kh < 2; ++kh) {
                    const unsigned char* Kr = sK + (tt*32 + kh*16 + fr) * 128;
                    short8 kfa = *(const short8*)(Kr + ((fg*16) ^ rswz));
                    short8 kfb = *(const short8*)(Kr + ((64 + fg*16) ^ rswz));
                    f32x4 zz = {0.f, 0.f, 0.f, 0.f};
                    zz = __builtin_amdgcn_mfma_f32_16x16x32_bf16(kfa, qf0, zz, 0, 0, 0);
                    zz = __builtin_amdgcn_mfma_f32_16x16x32_bf16(kfb, qf1, zz, 0, 0, 0);
                    z[kh] = zz;
                }

                const bool full = (kb2 + 31 <= q0);   // wave-uniform
                const int kq = kb2 + fg * 4;          // z0 key base, this lane
                const int qg = q0 + fr;
                float p[8];
                #pragma unroll
                for (int r = 0; r < 4; ++r) {
                    float s0 = z[0][r], s1 = z[1][r];
                    if (!full) {
                        s0 = (kq + r      <= qg) ? s0 : -1e30f;
                        s1 = (kq + 16 + r <= qg) ? s1 : -1e30f;
                    }
                    p[r]     = exp2f(s0);             // native v_exp_f32
                    p[4 + r] = exp2f(s1);
                }

                // pack P A-frag in-register (pos-order matches PERM5)
                unsigned int pw0, pw1, pw2, pw3;
                asm("v_cvt_pk_bf16_f32 %0, %1, %2" : "=v"(pw0) : "v"(p[0]), "v"(p[1]));
                asm("v_cvt_pk_bf16_f32 %0, %1, %2" : "=v"(pw1) : "v"(p[2]), "v"(p[3]));
                asm("v_cvt_pk_bf16_f32 %0, %1, %2" : "=v"(pw2) : "v"(p[4]), "v"(p[5]));
                asm("v_cvt_pk_bf16_f32 %0, %1, %2" : "=v"(pw3) : "v"(p[6]), "v"(p[7]));
                short8 pf;
                {
                    unsigned int tmp[4] = {pw0, pw1, pw2, pw3};
                    __builtin_memcpy(&pf, tmp, 16);
                }

                #pragma unroll
                for (int db = 0; db < 4; ++db) {
                    const unsigned char* Vr = sV + (db*16 + fr) * 128;
                    short8 vf = *(const short8*)(Vr + ((tt*64 + fg*16) ^ rswz));
                    o[db] = __builtin_amdgcn_mfma_f32_16x16x32_bf16(pf, vf, o[db], 0, 0, 0);
                }
                // denominator: o4 += P @ ones (same C layout as o[db])
                o4 = __builtin_amdgcn_mfma_f32_16x16x32_bf16(pf, ones, o4, 0, 0, 0);
            }
        }

        // output: o[db][r] = O[q=q0+fg*4+r][d=db*16+fr]; denom = o4[r]
        #pragma unroll
        for (int r = 0; r < 4; ++r) {
            const float invq = 1.f / o4[r];
            const int t = q0 + fg * 4 + r;
            #pragma unroll
            for (int db = 0; db < 4; ++db) {
                att[(size_t)(b * T_SEQ + t) * CDIM + h * 64 + db * 16 + fr] =
                    f2bf(o[db][r] * invq);
            }
        }
    }
}

// ---------------------------------------------------------------------------
// Orchestration. Inputs fp32 (by size), outputs fp32 (y,k,v).
// Workspace:
//   [ 0,16M)  q_ws bf16 (QSCALE-scaled);  wTp overlays after attn
//   [16,32M)  x_bf -> vT bf16 (key-permuted) after gemm0
//   [32,48M)  wTa -> attb bf16 after gemm0
//   [48,64M)  k_bf bf16 (ws_size >= 64 MiB confirmed in r12; fallback kept)
// ---------------------------------------------------------------------------
extern "C" void kernel_launch(void* const* d_in, const int* in_sizes, int n_in,
                              void* d_out, int out_size, void* d_ws, size_t ws_size,
                              hipStream_t stream) {
    (void)out_size;
    const float *x = nullptr, *w_attn = nullptr, *b_attn = nullptr,
                *w_proj = nullptr, *b_proj = nullptr;
    for (int i = 0; i < n_in; ++i) {
        switch (in_sizes[i]) {
            case 8388608: x      = (const float*)d_in[i]; break;
            case 3145728: w_attn = (const float*)d_in[i]; break;
            case 3072:    b_attn = (const float*)d_in[i]; break;
            case 1048576: w_proj = (const float*)d_in[i]; break;
            case 1024:    b_proj = (const float*)d_in[i]; break;
        }
    }
    if (!x || !w_attn || !b_attn || !w_proj || !b_proj) return;

    float* out = (float*)d_out;
    unsigned char* ws = (unsigned char*)d_ws;
    const bool big = ws_size >= (64ull << 20);

    u16* q_ws = (u16*)(ws);
    u16* wTp  = (u16*)(ws);
    u16* x_bf = (u16*)(ws + 16777216);
    u16* vT   = (u16*)(ws + 16777216);
    u16* wTa  = (u16*)(ws + 33554432);
    u16* attb = (u16*)(ws + 33554432);
    u16* k_bf = big ? (u16*)(ws + 50331648) : nullptr;

    cast_k<<<8192, 256, 0, stream>>>(x, x_bf, 2097152);
    transpose_k<1, 0><<<dim3(96, 32, 1), dim3(32, 8), 0, stream>>>(w_attn, wTa, 1024, 3072);
    gemm_k<0><<<dim3(24, 64), 256, 0, stream>>>(x_bf, wTa, b_attn, out, q_ws, k_bf, 1024);
    // v -> vT with PERM5 key permutation (matches attn's in-register P order)
    transpose_k<1, 1><<<dim3(2, 128, 32), dim3(32, 8), 0, stream>>>(out + 2 * (size_t)SEC, vT, 4096, 64);
    if (big)
        attn_k<1><<<1024, 256, 0, stream>>>(q_ws, nullptr, k_bf, vT, attb);
    else
        attn_k<0><<<1024, 256, 0, stream>>>(q_ws, out + SEC, nullptr, vT, attb);
    transpose_k<1, 0><<<dim3(32, 32, 1), dim3(32, 8), 0, stream>>>(w_proj, wTp, 1024, 1024);
    gemm_k<1><<<dim3(8, 64), 256, 0, stream>>>(attb, wTp, b_proj, out, nullptr, nullptr, 1024);
}